// Round 13
// baseline (633.217 us; speedup 1.0000x reference)
//
#include <hip/hip_runtime.h>
#include <hip/hip_bf16.h>
#include <stdint.h>

#define B_ 4
#define S_ 2048
#define H_ 1024
#define I_ 4096
#define E_ 8
#define CAP 640
#define NTOK (B_*S_)            // 8192
#define NBE  (B_*E_)            // 32

typedef _Float16 f16;
typedef f16 f16x8 __attribute__((ext_vector_type(8)));
typedef float f32x4 __attribute__((ext_vector_type(4)));

// workspace layout (bytes)
#define OFF_LOGITS 0u                          // 65536 f32
#define OFF_TOPKI  (256u*1024u)                // 20480 int
#define OFF_TOPKW  (OFF_TOPKI + 128u*1024u)    // 20480 f32
#define OFF_COUNTS (OFF_TOPKW + 128u*1024u)    // 8192 f32
#define OFF_SCAL   (OFF_COUNTS + 64u*1024u)    // 16 f32
#define OFF_XH     (1u<<20)                    // 8192*1024 f16   (16.8 MB)
#define OFF_WT     (18u<<20)                   // 8*4096*1024 f16 (67.1 MB) — w1t then w2t (reused)
#define OFF_MID    (86u<<20)                   // 20480*4096 f16  (167.8 MB) → high-water ~254 MB

__device__ __forceinline__ void gl_lds16(const void* g, void* l) {
    __builtin_amdgcn_global_load_lds(
        (const __attribute__((address_space(1))) uint32_t*)g,
        (__attribute__((address_space(3))) uint32_t*)l, 16, 0, 0);
}

// ------------------------------------------------ router (+ x → f16 fused) --
// NOTE: summation order is frozen — top-k selection depends on exact fp32
// logit ordering near capacity boundaries. Do not restructure this reduce.
__global__ void k_router(const float* __restrict__ x, const float* __restrict__ rw,
                         float* __restrict__ logits, float* __restrict__ scal,
                         f16* __restrict__ xh) {
    __shared__ float rwt[E_ * H_];
    __shared__ float part[4][9];
    int tid = threadIdx.x;
    for (int i = tid; i < E_ * H_; i += 256) {
        int h = i >> 3, e = i & 7;
        rwt[e * H_ + h] = rw[i];
    }
    __syncthreads();
    int w = tid >> 6, lane = tid & 63;
    int t = blockIdx.x * 4 + w;
    const float* xr = x + (size_t)t * H_;
    f16* xhr = xh + ((size_t)t << 10);
    float acc[E_];
#pragma unroll
    for (int e = 0; e < E_; ++e) acc[e] = 0.f;
    for (int it = 0; it < H_ / 64; ++it) {
        int h = lane + it * 64;
        float xv = xr[h];
        xhr[h] = (f16)xv;
#pragma unroll
        for (int e = 0; e < E_; ++e) acc[e] += xv * rwt[e * H_ + h];
    }
#pragma unroll
    for (int off = 32; off > 0; off >>= 1)
#pragma unroll
        for (int e = 0; e < E_; ++e) acc[e] += __shfl_down(acc[e], off);
    if (lane == 0) {
        int b = t >> 11, s = t & 2047;
        float m = acc[0];
#pragma unroll
        for (int e = 1; e < E_; ++e) m = fmaxf(m, acc[e]);
        float z = 0.f, ps = 0.f;
        float p[E_];
#pragma unroll
        for (int e = 0; e < E_; ++e) {
            logits[(size_t)((b << 3) + e) * S_ + s] = acc[e];
            z += acc[e] * acc[e];
            p[e] = expf(acc[e] - m);
            ps += p[e];
        }
        part[w][0] = z;
#pragma unroll
        for (int e = 0; e < E_; ++e) part[w][1 + e] = p[e] / ps;
    }
    __syncthreads();
    if (tid < 9) {
        float v = part[0][tid] + part[1][tid] + part[2][tid] + part[3][tid];
        atomicAdd(&scal[tid], v);
    }
}

// ----------------------------------------------------------------- top-k ----
// Exact top-CAP via 8x8-bit radix select on distinct u64 keys (same set &
// tie-break as jax.lax.top_k; slot order irrelevant — atomic combine).
__global__ void __launch_bounds__(1024) k_topk(const float* __restrict__ logits,
                                               int* __restrict__ tki,
                                               float* __restrict__ tkw,
                                               float* __restrict__ counts) {
    int be = blockIdx.x;
    const float* row = logits + (size_t)be * S_;
    __shared__ unsigned hist[256];
    __shared__ unsigned long long wmax[16];
    __shared__ float wsum[16];
    __shared__ unsigned long long sh_prefix;
    __shared__ unsigned sh_rem;
    __shared__ unsigned long long sh_max;
    __shared__ float sh_stot;
    __shared__ unsigned sh_cnt;
    int tid = threadIdx.x;

    unsigned u0 = __float_as_uint(row[tid]);
    u0 = (u0 & 0x80000000u) ? ~u0 : (u0 | 0x80000000u);
    unsigned long long k0 = ((unsigned long long)u0 << 32) | (unsigned)(~tid);
    unsigned u1 = __float_as_uint(row[tid + 1024]);
    u1 = (u1 & 0x80000000u) ? ~u1 : (u1 | 0x80000000u);
    unsigned long long k1 = ((unsigned long long)u1 << 32) | (unsigned)(~(tid + 1024));

    if (tid == 0) { sh_cnt = 0; sh_rem = CAP; sh_prefix = 0; }
    unsigned long long m = k0 > k1 ? k0 : k1;
#pragma unroll
    for (int off = 32; off > 0; off >>= 1) {
        unsigned long long o = __shfl_down(m, off);
        if (o > m) m = o;
    }
    if ((tid & 63) == 0) wmax[tid >> 6] = m;
    __syncthreads();
    if (tid == 0) {
        unsigned long long mm = wmax[0];
#pragma unroll
        for (int i = 1; i < 16; ++i) if (wmax[i] > mm) mm = wmax[i];
        sh_max = mm;
    }

    unsigned long long prefix = 0;
    for (int L = 0; L < 8; ++L) {
        int shift = 56 - 8 * L;
        if (tid < 256) hist[tid] = 0;
        __syncthreads();
        bool m0 = (L == 0) || (((k0 ^ prefix) >> (shift + 8)) == 0);
        if (m0) atomicAdd(&hist[(unsigned)((k0 >> shift) & 255)], 1u);
        bool m1 = (L == 0) || (((k1 ^ prefix) >> (shift + 8)) == 0);
        if (m1) atomicAdd(&hist[(unsigned)((k1 >> shift) & 255)], 1u);
        __syncthreads();
        if (tid < 64) {
            unsigned g0 = hist[tid * 4], g1 = hist[tid * 4 + 1];
            unsigned g2 = hist[tid * 4 + 2], g3 = hist[tid * 4 + 3];
            unsigned gs = g0 + g1 + g2 + g3;
            unsigned suf = gs;
#pragma unroll
            for (int off = 1; off < 64; off <<= 1) {
                unsigned o = __shfl_down(suf, off);
                if (tid + off < 64) suf += o;
            }
            unsigned remaining = sh_rem;
            unsigned before = suf - gs;
            if (before < remaining && remaining <= suf) {
                unsigned cum = before;
                int bsel = tid * 4;
                unsigned rem2 = 0;
                for (int b = tid * 4 + 3; b >= tid * 4; --b) {
                    unsigned h = hist[b];
                    cum += h;
                    if (cum >= remaining) { bsel = b; rem2 = remaining - (cum - h); break; }
                }
                sh_prefix = prefix | ((unsigned long long)(unsigned)bsel << shift);
                sh_rem = rem2;
            }
        }
        __syncthreads();
        prefix = sh_prefix;
    }
    unsigned long long T = prefix;

    unsigned vu = (unsigned)(sh_max >> 32);
    float vmax = __uint_as_float((vu & 0x80000000u) ? (vu ^ 0x80000000u) : ~vu);

    float ex0 = 0.f, ex1 = 0.f;
    int idx0 = 0, idx1 = 0;
    if (k0 >= T) {
        idx0 = (int)(~(unsigned)k0) & 2047;
        unsigned vb = (unsigned)(k0 >> 32);
        float v = __uint_as_float((vb & 0x80000000u) ? (vb ^ 0x80000000u) : ~vb);
        ex0 = expf(v - vmax);
    }
    if (k1 >= T) {
        idx1 = (int)(~(unsigned)k1) & 2047;
        unsigned vb = (unsigned)(k1 >> 32);
        float v = __uint_as_float((vb & 0x80000000u) ? (vb ^ 0x80000000u) : ~vb);
        ex1 = expf(v - vmax);
    }
    float s = ex0 + ex1;
#pragma unroll
    for (int off = 32; off > 0; off >>= 1) s += __shfl_down(s, off);
    if ((tid & 63) == 0) wsum[tid >> 6] = s;
    __syncthreads();
    if (tid == 0) {
        float t2 = 0.f;
#pragma unroll
        for (int i = 0; i < 16; ++i) t2 += wsum[i];
        sh_stot = t2;
    }
    __syncthreads();
    float stot = sh_stot;
    if (k0 >= T) {
        unsigned slot = atomicAdd(&sh_cnt, 1u);
        tki[be * CAP + slot] = idx0;
        tkw[be * CAP + slot] = ex0 / stot;
        atomicAdd(&counts[(be >> 3) * S_ + idx0], 1.0f);
    }
    if (k1 >= T) {
        unsigned slot = atomicAdd(&sh_cnt, 1u);
        tki[be * CAP + slot] = idx1;
        tkw[be * CAP + slot] = ex1 / stot;
        atomicAdd(&counts[(be >> 3) * S_ + idx1], 1.0f);
    }
}

// in: [E][R][C] f32 → out: [E][C][R] f16
template<int R, int C>
__global__ void __launch_bounds__(256) k_transpose(const float* __restrict__ in,
                                                   f16* __restrict__ out) {
    __shared__ f16 t[64][68];
    int e = blockIdx.z;
    const float* ine = in + (size_t)e * R * C;
    f16* oute = out + (size_t)e * R * C;
    int c0 = blockIdx.x << 6, r0 = blockIdx.y << 6;
    int tx = threadIdx.x & 15, ty = threadIdx.x >> 4;
#pragma unroll
    for (int p = 0; p < 4; ++p) {
        int r = ty + p * 16;
        float4 v = *(const float4*)(ine + (size_t)(r0 + r) * C + c0 + tx * 4);
        t[tx * 4 + 0][r] = (f16)v.x;
        t[tx * 4 + 1][r] = (f16)v.y;
        t[tx * 4 + 2][r] = (f16)v.z;
        t[tx * 4 + 3][r] = (f16)v.w;
    }
    __syncthreads();
#pragma unroll
    for (int p = 0; p < 4; ++p) {
        int c = ty + p * 16;
        *(ushort4*)(oute + (size_t)(c0 + c) * R + r0 + tx * 4) =
            *(const ushort4*)&t[c][tx * 4];
    }
}

// ============================ GEMM core geometry =============================
// EVIDENCE (R2-R12): perf tracks blocks/CU; every pipeline/schedule variant
// regressed or was neutral. R9/R12 structure is the empirical optimum:
// 128x128 tile, BK=64, SINGLE 32KB LDS buffer (8-slot XOR swizzle → 0
// conflicts), (256,4), unified regs 124 → 4 blocks/CU (16 waves), stage →
// sync → 32 MFMA → sync. Rows expert-major; expert == XCD chunk.
// R13: gemm2 K-split ×4 → grid 5120 = 5 EXACT rounds @4/CU (was 1280 = 1.25
// rounds → ~20% tail, the measured 838-vs-747 TF gemm1/gemm2 gap). Partials
// combined by the existing f32 atomic epilogue (R5-validated, absmax equal).

#define MFMA4(MI, A) \
    acc[MI][0] = __builtin_amdgcn_mfma_f32_16x16x32_f16(A, bf0, acc[MI][0], 0, 0, 0); \
    acc[MI][1] = __builtin_amdgcn_mfma_f32_16x16x32_f16(A, bf1, acc[MI][1], 0, 0, 0); \
    acc[MI][2] = __builtin_amdgcn_mfma_f32_16x16x32_f16(A, bf2, acc[MI][2], 0, 0, 0); \
    acc[MI][3] = __builtin_amdgcn_mfma_f32_16x16x32_f16(A, bf3, acc[MI][3], 0, 0, 0);

// ---------------------------------------------------------- GEMM1 (+SiLU) ---
// grid 5120 = 8 e × 20 rt × 32 ct; XCD chunk = one expert (640 blocks).
__global__ void __launch_bounds__(256, 4) k_gemm1(const f16* __restrict__ xh,
                                                  const f16* __restrict__ w1t,
                                                  const int* __restrict__ tki,
                                                  f16* __restrict__ mid) {
    __shared__ f16 As[128 * 64];   // 16 KB
    __shared__ f16 Bs[128 * 64];   // 16 KB
    int bid = blockIdx.x;
    int e = bid & 7;
    int r = bid >> 3;              // 0..639 within expert chunk
    int rt = r % 20;
    int ct = r / 20;               // 0..31
    int n0 = ct << 7;
    const f16* w1e = w1t + ((size_t)e << 22);
    int tid = threadIdx.x;
    int w = tid >> 6, l = tid & 63;
    int wm = w >> 1, wn = w & 1;

    int gch = (tid & 7) ^ ((tid >> 3) & 7);
    int dstb = (tid >> 6) << 9;    // wave-uniform f16 base; HW adds lane*16B
    const f16* aS[4];
    const f16* bS[4];
#pragma unroll
    for (int i = 0; i < 4; ++i) {
        int ri = i * 32 + (tid >> 3);
        int ge = rt * 128 + ri;
        int bb = ge / 640;
        int cc = ge - bb * 640;
        int tok = tki[((bb << 3) + e) * 640 + cc];
        aS[i] = xh + ((size_t)((bb << 11) + tok) << 10) + (gch << 3);
        bS[i] = w1e + ((size_t)(n0 + ri) << 10) + (gch << 3);
    }

    int fr = l & 15, c4 = l >> 4;
    int f7 = fr & 7;
    int arow = (wm << 6) + fr;
    int brow = (wn << 6) + fr;
    f32x4 acc[4][4];
#pragma unroll
    for (int mi = 0; mi < 4; ++mi)
#pragma unroll
        for (int ni = 0; ni < 4; ++ni) acc[mi][ni] = (f32x4){0.f, 0.f, 0.f, 0.f};

    const int NT = H_ / 64;   // 16
    for (int t = 0; t < NT; ++t) {
        int ko = t << 6;
#pragma unroll
        for (int i = 0; i < 4; ++i) {
            gl_lds16(aS[i] + ko, As + i * 2048 + dstb);
            gl_lds16(bS[i] + ko, Bs + i * 2048 + dstb);
        }
        __syncthreads();
#pragma unroll
        for (int kf = 0; kf < 2; ++kf) {
            int sl = (((kf << 2) | c4) ^ f7) << 3;
            f16x8 bf0 = *(const f16x8*)(Bs + brow * 64 + sl);
            f16x8 bf1 = *(const f16x8*)(Bs + (brow + 16) * 64 + sl);
            f16x8 bf2 = *(const f16x8*)(Bs + (brow + 32) * 64 + sl);
            f16x8 bf3 = *(const f16x8*)(Bs + (brow + 48) * 64 + sl);
            f16x8 a0 = *(const f16x8*)(As + arow * 64 + sl);
            f16x8 a1 = *(const f16x8*)(As + (arow + 16) * 64 + sl);
            f16x8 a2 = *(const f16x8*)(As + (arow + 32) * 64 + sl);
            f16x8 a3 = *(const f16x8*)(As + (arow + 48) * 64 + sl);
            MFMA4(0, a0) MFMA4(1, a1) MFMA4(2, a2) MFMA4(3, a3)
        }
        __syncthreads();
    }

    // epilogue: FAST SiLU (v_exp + v_rcp; rel err ~1e-6 << f16 quantization)
    int rq4 = c4 << 2;
#pragma unroll
    for (int mi = 0; mi < 4; ++mi) {
#pragma unroll
        for (int q = 0; q < 4; ++q) {
            int row = (wm << 6) + mi * 16 + rq4 + q;
            int ge = rt * 128 + row;
            int bb = ge / 640;
            int cc = ge - bb * 640;
            size_t flat = (size_t)(((bb << 3) + e) * 640 + cc);
            f16* mrow = mid + (flat << 12) + n0 + (wn << 6) + fr;
#pragma unroll
            for (int ni = 0; ni < 4; ++ni) {
                float v = acc[mi][ni][q];
                v = v * __builtin_amdgcn_rcpf(1.f + __expf(-v));
                mrow[ni * 16] = (f16)v;
            }
        }
    }
}

// ------------------------------------------- GEMM2 + weighted atomic scatter
// grid 5120 = 8 e × [ks4 × rt20 × ct8]; XCD chunk = one expert (640 blocks).
// K-split ×4 (ks slowest within chunk → same-address atomics time-separated);
// each block: K=1024 (16 iters). LDS exactly 32768 B.
__global__ void __launch_bounds__(256, 4) k_gemm2(const f16* __restrict__ mid,
                                                  const f16* __restrict__ w2t,
                                                  const int* __restrict__ tki,
                                                  const float* __restrict__ tkw,
                                                  float* __restrict__ out) {
    __shared__ f16 As[128 * 64];
    __shared__ f16 Bs[128 * 64];
    int bid = blockIdx.x;
    int e = bid & 7;
    int r = bid >> 3;              // 0..639
    int ct = r & 7;                // 0..7
    int rk = r >> 3;               // 0..79
    int rt = rk % 20;
    int ks = rk / 20;              // 0..3
    int n0 = ct << 7;
    const f16* w2e = w2t + ((size_t)e << 22);
    int tid = threadIdx.x;
    int w = tid >> 6, l = tid & 63;
    int wm = w >> 1, wn = w & 1;

    int gch = (tid & 7) ^ ((tid >> 3) & 7);
    int dstb = (tid >> 6) << 9;
    const f16* aS[4];
    const f16* bS[4];
#pragma unroll
    for (int i = 0; i < 4; ++i) {
        int ri = i * 32 + (tid >> 3);
        int ge = rt * 128 + ri;
        int bb = ge / 640;
        int cc = ge - bb * 640;
        size_t flat = (size_t)(((bb << 3) + e) * 640 + cc);
        aS[i] = mid + (flat << 12) + (ks << 10) + (gch << 3);
        bS[i] = w2e + ((size_t)(n0 + ri) << 12) + (ks << 10) + (gch << 3);
    }

    int fr = l & 15, c4 = l >> 4;
    int f7 = fr & 7;
    int arow = (wm << 6) + fr;
    int brow = (wn << 6) + fr;
    f32x4 acc[4][4];
#pragma unroll
    for (int mi = 0; mi < 4; ++mi)
#pragma unroll
        for (int ni = 0; ni < 4; ++ni) acc[mi][ni] = (f32x4){0.f, 0.f, 0.f, 0.f};

    const int NT = 16;   // K=1024 slice per block
    for (int t = 0; t < NT; ++t) {
        int ko = t << 6;
#pragma unroll
        for (int i = 0; i < 4; ++i) {
            gl_lds16(aS[i] + ko, As + i * 2048 + dstb);
            gl_lds16(bS[i] + ko, Bs + i * 2048 + dstb);
        }
        __syncthreads();
#pragma unroll
        for (int kf = 0; kf < 2; ++kf) {
            int sl = (((kf << 2) | c4) ^ f7) << 3;
            f16x8 bf0 = *(const f16x8*)(Bs + brow * 64 + sl);
            f16x8 bf1 = *(const f16x8*)(Bs + (brow + 16) * 64 + sl);
            f16x8 bf2 = *(const f16x8*)(Bs + (brow + 32) * 64 + sl);
            f16x8 bf3 = *(const f16x8*)(Bs + (brow + 48) * 64 + sl);
            f16x8 a0 = *(const f16x8*)(As + arow * 64 + sl);
            f16x8 a1 = *(const f16x8*)(As + (arow + 16) * 64 + sl);
            f16x8 a2 = *(const f16x8*)(As + (arow + 32) * 64 + sl);
            f16x8 a3 = *(const f16x8*)(As + (arow + 48) * 64 + sl);
            MFMA4(0, a0) MFMA4(1, a1) MFMA4(2, a2) MFMA4(3, a3)
        }
        __syncthreads();
    }

    // stage row offsets/weights into dead LDS (As is free after final barrier)
    int* rowOffS = (int*)As;              // 512 B
    float* wtsS = (float*)(As + 256);     // 512 B
    if (tid < 128) {
        int ge = rt * 128 + tid;
        int bb = ge / 640;
        int cc = ge - bb * 640;
        int flat = ((bb << 3) + e) * 640 + cc;
        rowOffS[tid] = ((bb << 11) + tki[flat]) << 10;
        wtsS[tid] = tkw[flat];
    }
    __syncthreads();

    int rq4 = c4 << 2;
#pragma unroll
    for (int mi = 0; mi < 4; ++mi) {
#pragma unroll
        for (int q = 0; q < 4; ++q) {
            int row = (wm << 6) + mi * 16 + rq4 + q;
            int ro = rowOffS[row] + n0 + (wn << 6) + fr;
            float wg = wtsS[row];
#pragma unroll
            for (int ni = 0; ni < 4; ++ni) {
                atomicAdd(&out[ro + ni * 16], acc[mi][ni][q] * wg);
            }
        }
    }
}

// ------------------------------------------------- normalize + loss ---------
__global__ void k_final(float* __restrict__ out, const float* __restrict__ counts,
                        const float* __restrict__ scal, float* __restrict__ loss_out) {
    size_t gid = (size_t)blockIdx.x * 256 + threadIdx.x;
    int tok = (int)(gid >> 8);
    float c = fmaxf(counts[tok], 1.0f);
    float4* o4 = (float4*)out;
    float4 v = o4[gid];
    v.x /= c; v.y /= c; v.z /= c; v.w /= c;
    o4[gid] = v;
    if (gid == 0) {
        float z = scal[0] / (float)(NTOK * E_);
        float aux = 0.f;
#pragma unroll
        for (int e = 0; e < E_; ++e) {
            float u = scal[1 + e] / (float)NTOK - 0.125f;
            aux += u * u;
        }
        loss_out[0] = 0.01f * aux + 0.001f * z;
    }
}

// ----------------------------------------------------------------------------
extern "C" void kernel_launch(void* const* d_in, const int* in_sizes, int n_in,
                              void* d_out, int out_size, void* d_ws, size_t ws_size,
                              hipStream_t stream) {
    const float* x  = (const float*)d_in[0];
    const float* rw = (const float*)d_in[1];
    const float* w1 = (const float*)d_in[2];
    const float* w2 = (const float*)d_in[3];
    float* out = (float*)d_out;
    char* ws = (char*)d_ws;

    float* logits = (float*)(ws + OFF_LOGITS);
    int*   tki    = (int*)(ws + OFF_TOPKI);
    float* tkw    = (float*)(ws + OFF_TOPKW);
    float* counts = (float*)(ws + OFF_COUNTS);
    float* scal   = (float*)(ws + OFF_SCAL);
    f16*   xh     = (f16*)(ws + OFF_XH);
    f16*   wt     = (f16*)(ws + OFF_WT);     // w1t, then reused as w2t
    f16*   mid    = (f16*)(ws + OFF_MID);

    hipMemsetAsync(ws + OFF_COUNTS, 0, 64u * 1024u + 64u, stream);
    hipMemsetAsync(d_out, 0, (size_t)out_size * sizeof(float), stream);

    k_transpose<H_, I_><<<dim3(I_ / 64, H_ / 64, E_), 256, 0, stream>>>(w1, wt);
    k_router<<<NTOK / 4, 256, 0, stream>>>(x, rw, logits, scal, xh);
    k_topk<<<NBE, 1024, 0, stream>>>(logits, tki, tkw, counts);
    k_gemm1<<<5120, 256, 0, stream>>>(xh, wt, tki, mid);
    // reuse WT region for w2t (stream-ordered after gemm1 finished reading w1t)
    k_transpose<I_, H_><<<dim3(H_ / 64, I_ / 64, E_), 256, 0, stream>>>(w2, wt);
    k_gemm2<<<5120, 256, 0, stream>>>(mid, wt, tki, tkw, out);
    k_final<<<(NTOK * H_ / 4) / 256, 256, 0, stream>>>(out, counts, scal,
                                                       out + (size_t)NTOK * H_);
}

// Round 14
// 589.909 us; speedup vs baseline: 1.0734x; 1.0734x over previous
//
#include <hip/hip_runtime.h>
#include <hip/hip_bf16.h>
#include <stdint.h>

#define B_ 4
#define S_ 2048
#define H_ 1024
#define I_ 4096
#define E_ 8
#define CAP 640
#define NTOK (B_*S_)            // 8192
#define NBE  (B_*E_)            // 32

typedef _Float16 f16;
typedef f16 f16x8 __attribute__((ext_vector_type(8)));
typedef float f32x4 __attribute__((ext_vector_type(4)));

// workspace layout (bytes)
#define OFF_LOGITS 0u                          // 65536 f32
#define OFF_TOPKI  (256u*1024u)                // 20480 int
#define OFF_TOPKW  (OFF_TOPKI + 128u*1024u)    // 20480 f32
#define OFF_COUNTS (OFF_TOPKW + 128u*1024u)    // 8192 f32
#define OFF_SCAL   (OFF_COUNTS + 64u*1024u)    // 16 f32
#define OFF_XH     (1u<<20)                    // 8192*1024 f16   (16.8 MB)
#define OFF_WT     (18u<<20)                   // 8*4096*1024 f16 (67.1 MB) — w1t then w2t (reused)
#define OFF_MID    (86u<<20)                   // 20480*4096 f16  (167.8 MB) → high-water ~254 MB

__device__ __forceinline__ void gl_lds16(const void* g, void* l) {
    __builtin_amdgcn_global_load_lds(
        (const __attribute__((address_space(1))) uint32_t*)g,
        (__attribute__((address_space(3))) uint32_t*)l, 16, 0, 0);
}

// ------------------------------------------------ router (+ x → f16 fused) --
// NOTE: summation order is frozen — top-k selection depends on exact fp32
// logit ordering near capacity boundaries. Do not restructure this reduce.
__global__ void k_router(const float* __restrict__ x, const float* __restrict__ rw,
                         float* __restrict__ logits, float* __restrict__ scal,
                         f16* __restrict__ xh) {
    __shared__ float rwt[E_ * H_];
    __shared__ float part[4][9];
    int tid = threadIdx.x;
    for (int i = tid; i < E_ * H_; i += 256) {
        int h = i >> 3, e = i & 7;
        rwt[e * H_ + h] = rw[i];
    }
    __syncthreads();
    int w = tid >> 6, lane = tid & 63;
    int t = blockIdx.x * 4 + w;
    const float* xr = x + (size_t)t * H_;
    f16* xhr = xh + ((size_t)t << 10);
    float acc[E_];
#pragma unroll
    for (int e = 0; e < E_; ++e) acc[e] = 0.f;
    for (int it = 0; it < H_ / 64; ++it) {
        int h = lane + it * 64;
        float xv = xr[h];
        xhr[h] = (f16)xv;
#pragma unroll
        for (int e = 0; e < E_; ++e) acc[e] += xv * rwt[e * H_ + h];
    }
#pragma unroll
    for (int off = 32; off > 0; off >>= 1)
#pragma unroll
        for (int e = 0; e < E_; ++e) acc[e] += __shfl_down(acc[e], off);
    if (lane == 0) {
        int b = t >> 11, s = t & 2047;
        float m = acc[0];
#pragma unroll
        for (int e = 1; e < E_; ++e) m = fmaxf(m, acc[e]);
        float z = 0.f, ps = 0.f;
        float p[E_];
#pragma unroll
        for (int e = 0; e < E_; ++e) {
            logits[(size_t)((b << 3) + e) * S_ + s] = acc[e];
            z += acc[e] * acc[e];
            p[e] = expf(acc[e] - m);
            ps += p[e];
        }
        part[w][0] = z;
#pragma unroll
        for (int e = 0; e < E_; ++e) part[w][1 + e] = p[e] / ps;
    }
    __syncthreads();
    if (tid < 9) {
        float v = part[0][tid] + part[1][tid] + part[2][tid] + part[3][tid];
        atomicAdd(&scal[tid], v);
    }
}

// ----------------------------------------------------------------- top-k ----
// Exact top-CAP via 8x8-bit radix select on distinct u64 keys (same set &
// tie-break as jax.lax.top_k; slot order irrelevant — atomic combine).
__global__ void __launch_bounds__(1024) k_topk(const float* __restrict__ logits,
                                               int* __restrict__ tki,
                                               float* __restrict__ tkw,
                                               float* __restrict__ counts) {
    int be = blockIdx.x;
    const float* row = logits + (size_t)be * S_;
    __shared__ unsigned hist[256];
    __shared__ unsigned long long wmax[16];
    __shared__ float wsum[16];
    __shared__ unsigned long long sh_prefix;
    __shared__ unsigned sh_rem;
    __shared__ unsigned long long sh_max;
    __shared__ float sh_stot;
    __shared__ unsigned sh_cnt;
    int tid = threadIdx.x;

    unsigned u0 = __float_as_uint(row[tid]);
    u0 = (u0 & 0x80000000u) ? ~u0 : (u0 | 0x80000000u);
    unsigned long long k0 = ((unsigned long long)u0 << 32) | (unsigned)(~tid);
    unsigned u1 = __float_as_uint(row[tid + 1024]);
    u1 = (u1 & 0x80000000u) ? ~u1 : (u1 | 0x80000000u);
    unsigned long long k1 = ((unsigned long long)u1 << 32) | (unsigned)(~(tid + 1024));

    if (tid == 0) { sh_cnt = 0; sh_rem = CAP; sh_prefix = 0; }
    unsigned long long m = k0 > k1 ? k0 : k1;
#pragma unroll
    for (int off = 32; off > 0; off >>= 1) {
        unsigned long long o = __shfl_down(m, off);
        if (o > m) m = o;
    }
    if ((tid & 63) == 0) wmax[tid >> 6] = m;
    __syncthreads();
    if (tid == 0) {
        unsigned long long mm = wmax[0];
#pragma unroll
        for (int i = 1; i < 16; ++i) if (wmax[i] > mm) mm = wmax[i];
        sh_max = mm;
    }

    unsigned long long prefix = 0;
    for (int L = 0; L < 8; ++L) {
        int shift = 56 - 8 * L;
        if (tid < 256) hist[tid] = 0;
        __syncthreads();
        bool m0 = (L == 0) || (((k0 ^ prefix) >> (shift + 8)) == 0);
        if (m0) atomicAdd(&hist[(unsigned)((k0 >> shift) & 255)], 1u);
        bool m1 = (L == 0) || (((k1 ^ prefix) >> (shift + 8)) == 0);
        if (m1) atomicAdd(&hist[(unsigned)((k1 >> shift) & 255)], 1u);
        __syncthreads();
        if (tid < 64) {
            unsigned g0 = hist[tid * 4], g1 = hist[tid * 4 + 1];
            unsigned g2 = hist[tid * 4 + 2], g3 = hist[tid * 4 + 3];
            unsigned gs = g0 + g1 + g2 + g3;
            unsigned suf = gs;
#pragma unroll
            for (int off = 1; off < 64; off <<= 1) {
                unsigned o = __shfl_down(suf, off);
                if (tid + off < 64) suf += o;
            }
            unsigned remaining = sh_rem;
            unsigned before = suf - gs;
            if (before < remaining && remaining <= suf) {
                unsigned cum = before;
                int bsel = tid * 4;
                unsigned rem2 = 0;
                for (int b = tid * 4 + 3; b >= tid * 4; --b) {
                    unsigned h = hist[b];
                    cum += h;
                    if (cum >= remaining) { bsel = b; rem2 = remaining - (cum - h); break; }
                }
                sh_prefix = prefix | ((unsigned long long)(unsigned)bsel << shift);
                sh_rem = rem2;
            }
        }
        __syncthreads();
        prefix = sh_prefix;
    }
    unsigned long long T = prefix;

    unsigned vu = (unsigned)(sh_max >> 32);
    float vmax = __uint_as_float((vu & 0x80000000u) ? (vu ^ 0x80000000u) : ~vu);

    float ex0 = 0.f, ex1 = 0.f;
    int idx0 = 0, idx1 = 0;
    if (k0 >= T) {
        idx0 = (int)(~(unsigned)k0) & 2047;
        unsigned vb = (unsigned)(k0 >> 32);
        float v = __uint_as_float((vb & 0x80000000u) ? (vb ^ 0x80000000u) : ~vb);
        ex0 = expf(v - vmax);
    }
    if (k1 >= T) {
        idx1 = (int)(~(unsigned)k1) & 2047;
        unsigned vb = (unsigned)(k1 >> 32);
        float v = __uint_as_float((vb & 0x80000000u) ? (vb ^ 0x80000000u) : ~vb);
        ex1 = expf(v - vmax);
    }
    float s = ex0 + ex1;
#pragma unroll
    for (int off = 32; off > 0; off >>= 1) s += __shfl_down(s, off);
    if ((tid & 63) == 0) wsum[tid >> 6] = s;
    __syncthreads();
    if (tid == 0) {
        float t2 = 0.f;
#pragma unroll
        for (int i = 0; i < 16; ++i) t2 += wsum[i];
        sh_stot = t2;
    }
    __syncthreads();
    float stot = sh_stot;
    if (k0 >= T) {
        unsigned slot = atomicAdd(&sh_cnt, 1u);
        tki[be * CAP + slot] = idx0;
        tkw[be * CAP + slot] = ex0 / stot;
        atomicAdd(&counts[(be >> 3) * S_ + idx0], 1.0f);
    }
    if (k1 >= T) {
        unsigned slot = atomicAdd(&sh_cnt, 1u);
        tki[be * CAP + slot] = idx1;
        tkw[be * CAP + slot] = ex1 / stot;
        atomicAdd(&counts[(be >> 3) * S_ + idx1], 1.0f);
    }
}

// in: [E][R][C] f32 → out: [E][C][R] f16
template<int R, int C>
__global__ void __launch_bounds__(256) k_transpose(const float* __restrict__ in,
                                                   f16* __restrict__ out) {
    __shared__ f16 t[64][68];
    int e = blockIdx.z;
    const float* ine = in + (size_t)e * R * C;
    f16* oute = out + (size_t)e * R * C;
    int c0 = blockIdx.x << 6, r0 = blockIdx.y << 6;
    int tx = threadIdx.x & 15, ty = threadIdx.x >> 4;
#pragma unroll
    for (int p = 0; p < 4; ++p) {
        int r = ty + p * 16;
        float4 v = *(const float4*)(ine + (size_t)(r0 + r) * C + c0 + tx * 4);
        t[tx * 4 + 0][r] = (f16)v.x;
        t[tx * 4 + 1][r] = (f16)v.y;
        t[tx * 4 + 2][r] = (f16)v.z;
        t[tx * 4 + 3][r] = (f16)v.w;
    }
    __syncthreads();
#pragma unroll
    for (int p = 0; p < 4; ++p) {
        int c = ty + p * 16;
        *(ushort4*)(oute + (size_t)(c0 + c) * R + r0 + tx * 4) =
            *(const ushort4*)&t[c][tx * 4];
    }
}

// ============================ GEMM core geometry =============================
// EVIDENCE (R2-R13): perf tracks blocks/CU; every schedule variant regressed
// or neutral; K-split atomics regressed (R13: WRITE ×4, MfmaUtil 33→23).
// R12 base: 128x128 tile, BK=64, single 32KB LDS buffer (8-slot XOR swizzle →
// 0 conflicts), stage → sync → 32 MFMA → sync. Rows expert-major; expert ==
// XCD chunk. R14: gemm2 retiled 64x128 → acc[2][4] (~85 regs) → 5 blocks/CU
// under (256,5); grid 2560 = 2 EXACT rounds of 5 — kills the 1.25-round tail
// WITHOUT extra atomics (each out element written once, as in R12).

#define MFMA4(MI, A) \
    acc[MI][0] = __builtin_amdgcn_mfma_f32_16x16x32_f16(A, bf0, acc[MI][0], 0, 0, 0); \
    acc[MI][1] = __builtin_amdgcn_mfma_f32_16x16x32_f16(A, bf1, acc[MI][1], 0, 0, 0); \
    acc[MI][2] = __builtin_amdgcn_mfma_f32_16x16x32_f16(A, bf2, acc[MI][2], 0, 0, 0); \
    acc[MI][3] = __builtin_amdgcn_mfma_f32_16x16x32_f16(A, bf3, acc[MI][3], 0, 0, 0);

// ---------------------------------------------------------- GEMM1 (+SiLU) ---
// grid 5120 = 8 e × 20 rt × 32 ct; XCD chunk = one expert (640 blocks).
// Unchanged from R12 (205 µs, 5 exact rounds @4/CU, ~838 TF).
__global__ void __launch_bounds__(256, 4) k_gemm1(const f16* __restrict__ xh,
                                                  const f16* __restrict__ w1t,
                                                  const int* __restrict__ tki,
                                                  f16* __restrict__ mid) {
    __shared__ f16 As[128 * 64];   // 16 KB
    __shared__ f16 Bs[128 * 64];   // 16 KB
    int bid = blockIdx.x;
    int e = bid & 7;
    int r = bid >> 3;              // 0..639 within expert chunk
    int rt = r % 20;
    int ct = r / 20;               // 0..31
    int n0 = ct << 7;
    const f16* w1e = w1t + ((size_t)e << 22);
    int tid = threadIdx.x;
    int w = tid >> 6, l = tid & 63;
    int wm = w >> 1, wn = w & 1;

    int gch = (tid & 7) ^ ((tid >> 3) & 7);
    int dstb = (tid >> 6) << 9;    // wave-uniform f16 base; HW adds lane*16B
    const f16* aS[4];
    const f16* bS[4];
#pragma unroll
    for (int i = 0; i < 4; ++i) {
        int ri = i * 32 + (tid >> 3);
        int ge = rt * 128 + ri;
        int bb = ge / 640;
        int cc = ge - bb * 640;
        int tok = tki[((bb << 3) + e) * 640 + cc];
        aS[i] = xh + ((size_t)((bb << 11) + tok) << 10) + (gch << 3);
        bS[i] = w1e + ((size_t)(n0 + ri) << 10) + (gch << 3);
    }

    int fr = l & 15, c4 = l >> 4;
    int f7 = fr & 7;
    int arow = (wm << 6) + fr;
    int brow = (wn << 6) + fr;
    f32x4 acc[4][4];
#pragma unroll
    for (int mi = 0; mi < 4; ++mi)
#pragma unroll
        for (int ni = 0; ni < 4; ++ni) acc[mi][ni] = (f32x4){0.f, 0.f, 0.f, 0.f};

    const int NT = H_ / 64;   // 16
    for (int t = 0; t < NT; ++t) {
        int ko = t << 6;
#pragma unroll
        for (int i = 0; i < 4; ++i) {
            gl_lds16(aS[i] + ko, As + i * 2048 + dstb);
            gl_lds16(bS[i] + ko, Bs + i * 2048 + dstb);
        }
        __syncthreads();
#pragma unroll
        for (int kf = 0; kf < 2; ++kf) {
            int sl = (((kf << 2) | c4) ^ f7) << 3;
            f16x8 bf0 = *(const f16x8*)(Bs + brow * 64 + sl);
            f16x8 bf1 = *(const f16x8*)(Bs + (brow + 16) * 64 + sl);
            f16x8 bf2 = *(const f16x8*)(Bs + (brow + 32) * 64 + sl);
            f16x8 bf3 = *(const f16x8*)(Bs + (brow + 48) * 64 + sl);
            f16x8 a0 = *(const f16x8*)(As + arow * 64 + sl);
            f16x8 a1 = *(const f16x8*)(As + (arow + 16) * 64 + sl);
            f16x8 a2 = *(const f16x8*)(As + (arow + 32) * 64 + sl);
            f16x8 a3 = *(const f16x8*)(As + (arow + 48) * 64 + sl);
            MFMA4(0, a0) MFMA4(1, a1) MFMA4(2, a2) MFMA4(3, a3)
        }
        __syncthreads();
    }

    // epilogue: FAST SiLU (v_exp + v_rcp; rel err ~1e-6 << f16 quantization)
    int rq4 = c4 << 2;
#pragma unroll
    for (int mi = 0; mi < 4; ++mi) {
#pragma unroll
        for (int q = 0; q < 4; ++q) {
            int row = (wm << 6) + mi * 16 + rq4 + q;
            int ge = rt * 128 + row;
            int bb = ge / 640;
            int cc = ge - bb * 640;
            size_t flat = (size_t)(((bb << 3) + e) * 640 + cc);
            f16* mrow = mid + (flat << 12) + n0 + (wn << 6) + fr;
#pragma unroll
            for (int ni = 0; ni < 4; ++ni) {
                float v = acc[mi][ni][q];
                v = v * __builtin_amdgcn_rcpf(1.f + __expf(-v));
                mrow[ni * 16] = (f16)v;
            }
        }
    }
}

// ------------------------------------------- GEMM2 + weighted atomic scatter
// grid 2560 = 8 e × 40 rt × 8 ct; XCD chunk = one expert (320 blocks).
// 64x128 tile, full K=4096 per block (no extra atomics). acc[2][4] → ~85
// regs → 5 blocks/CU under (256,5); 2560/256 = 2 exact rounds. LDS 24 KB.
__global__ void __launch_bounds__(256, 5) k_gemm2(const f16* __restrict__ mid,
                                                  const f16* __restrict__ w2t,
                                                  const int* __restrict__ tki,
                                                  const float* __restrict__ tkw,
                                                  float* __restrict__ out) {
    __shared__ f16 As[64 * 64];    // 8 KB
    __shared__ f16 Bs[128 * 64];   // 16 KB
    int bid = blockIdx.x;
    int e = bid & 7;
    int r = bid >> 3;              // 0..319
    int rt = r % 40;
    int ct = r / 40;               // 0..7
    int n0 = ct << 7;
    const f16* w2e = w2t + ((size_t)e << 22);
    int tid = threadIdx.x;
    int w = tid >> 6, l = tid & 63;
    int wm = w >> 1, wn = w & 1;   // wave tile: 32 rows x 64 cols

    int gch = (tid & 7) ^ ((tid >> 3) & 7);
    int dstb = (tid >> 6) << 9;
    const f16* aS[2];
    const f16* bS[4];
#pragma unroll
    for (int i = 0; i < 2; ++i) {
        int ri = i * 32 + (tid >> 3);
        int ge = rt * 64 + ri;
        int bb = ge / 640;
        int cc = ge - bb * 640;
        size_t flat = (size_t)(((bb << 3) + e) * 640 + cc);
        aS[i] = mid + (flat << 12) + (gch << 3);
    }
#pragma unroll
    for (int i = 0; i < 4; ++i) {
        int ri = i * 32 + (tid >> 3);
        bS[i] = w2e + ((size_t)(n0 + ri) << 12) + (gch << 3);
    }

    int fr = l & 15, c4 = l >> 4;
    int f7 = fr & 7;
    int arow = (wm << 5) + fr;     // + mi*16
    int brow = (wn << 6) + fr;     // + ni*16
    f32x4 acc[2][4];
#pragma unroll
    for (int mi = 0; mi < 2; ++mi)
#pragma unroll
        for (int ni = 0; ni < 4; ++ni) acc[mi][ni] = (f32x4){0.f, 0.f, 0.f, 0.f};

    const int NT = I_ / 64;   // 64
    for (int t = 0; t < NT; ++t) {
        int ko = t << 6;
        gl_lds16(aS[0] + ko, As + dstb);
        gl_lds16(aS[1] + ko, As + 2048 + dstb);
#pragma unroll
        for (int i = 0; i < 4; ++i)
            gl_lds16(bS[i] + ko, Bs + i * 2048 + dstb);
        __syncthreads();
#pragma unroll
        for (int kf = 0; kf < 2; ++kf) {
            int sl = (((kf << 2) | c4) ^ f7) << 3;
            f16x8 bf0 = *(const f16x8*)(Bs + brow * 64 + sl);
            f16x8 bf1 = *(const f16x8*)(Bs + (brow + 16) * 64 + sl);
            f16x8 bf2 = *(const f16x8*)(Bs + (brow + 32) * 64 + sl);
            f16x8 bf3 = *(const f16x8*)(Bs + (brow + 48) * 64 + sl);
            f16x8 a0 = *(const f16x8*)(As + arow * 64 + sl);
            f16x8 a1 = *(const f16x8*)(As + (arow + 16) * 64 + sl);
            MFMA4(0, a0) MFMA4(1, a1)
        }
        __syncthreads();
    }

    // stage row offsets/weights into dead LDS (As is free after final barrier)
    int* rowOffS = (int*)As;              // 256 B
    float* wtsS = (float*)(As + 128);     // 256 B
    if (tid < 64) {
        int ge = rt * 64 + tid;
        int bb = ge / 640;
        int cc = ge - bb * 640;
        int flat = ((bb << 3) + e) * 640 + cc;
        rowOffS[tid] = ((bb << 11) + tki[flat]) << 10;
        wtsS[tid] = tkw[flat];
    }
    __syncthreads();

    int rq4 = c4 << 2;
#pragma unroll
    for (int mi = 0; mi < 2; ++mi) {
#pragma unroll
        for (int q = 0; q < 4; ++q) {
            int row = (wm << 5) + mi * 16 + rq4 + q;
            int ro = rowOffS[row] + n0 + (wn << 6) + fr;
            float wg = wtsS[row];
#pragma unroll
            for (int ni = 0; ni < 4; ++ni) {
                atomicAdd(&out[ro + ni * 16], acc[mi][ni][q] * wg);
            }
        }
    }
}

// ------------------------------------------------- normalize + loss ---------
__global__ void k_final(float* __restrict__ out, const float* __restrict__ counts,
                        const float* __restrict__ scal, float* __restrict__ loss_out) {
    size_t gid = (size_t)blockIdx.x * 256 + threadIdx.x;
    int tok = (int)(gid >> 8);
    float c = fmaxf(counts[tok], 1.0f);
    float4* o4 = (float4*)out;
    float4 v = o4[gid];
    v.x /= c; v.y /= c; v.z /= c; v.w /= c;
    o4[gid] = v;
    if (gid == 0) {
        float z = scal[0] / (float)(NTOK * E_);
        float aux = 0.f;
#pragma unroll
        for (int e = 0; e < E_; ++e) {
            float u = scal[1 + e] / (float)NTOK - 0.125f;
            aux += u * u;
        }
        loss_out[0] = 0.01f * aux + 0.001f * z;
    }
}

// ----------------------------------------------------------------------------
extern "C" void kernel_launch(void* const* d_in, const int* in_sizes, int n_in,
                              void* d_out, int out_size, void* d_ws, size_t ws_size,
                              hipStream_t stream) {
    const float* x  = (const float*)d_in[0];
    const float* rw = (const float*)d_in[1];
    const float* w1 = (const float*)d_in[2];
    const float* w2 = (const float*)d_in[3];
    float* out = (float*)d_out;
    char* ws = (char*)d_ws;

    float* logits = (float*)(ws + OFF_LOGITS);
    int*   tki    = (int*)(ws + OFF_TOPKI);
    float* tkw    = (float*)(ws + OFF_TOPKW);
    float* counts = (float*)(ws + OFF_COUNTS);
    float* scal   = (float*)(ws + OFF_SCAL);
    f16*   xh     = (f16*)(ws + OFF_XH);
    f16*   wt     = (f16*)(ws + OFF_WT);     // w1t, then reused as w2t
    f16*   mid    = (f16*)(ws + OFF_MID);

    hipMemsetAsync(ws + OFF_COUNTS, 0, 64u * 1024u + 64u, stream);
    hipMemsetAsync(d_out, 0, (size_t)out_size * sizeof(float), stream);

    k_transpose<H_, I_><<<dim3(I_ / 64, H_ / 64, E_), 256, 0, stream>>>(w1, wt);
    k_router<<<NTOK / 4, 256, 0, stream>>>(x, rw, logits, scal, xh);
    k_topk<<<NBE, 1024, 0, stream>>>(logits, tki, tkw, counts);
    k_gemm1<<<5120, 256, 0, stream>>>(xh, wt, tki, mid);
    // reuse WT region for w2t (stream-ordered after gemm1 finished reading w1t)
    k_transpose<I_, H_><<<dim3(H_ / 64, I_ / 64, E_), 256, 0, stream>>>(w2, wt);
    k_gemm2<<<2560, 256, 0, stream>>>(mid, wt, tki, tkw, out);
    k_final<<<(NTOK * H_ / 4) / 256, 256, 0, stream>>>(out, counts, scal,
                                                       out + (size_t)NTOK * H_);
}

// Round 15
// 565.232 us; speedup vs baseline: 1.1203x; 1.0437x over previous
//
#include <hip/hip_runtime.h>
#include <hip/hip_bf16.h>
#include <stdint.h>

#define B_ 4
#define S_ 2048
#define H_ 1024
#define I_ 4096
#define E_ 8
#define CAP 640
#define NTOK (B_*S_)            // 8192
#define NBE  (B_*E_)            // 32

typedef _Float16 f16;
typedef f16 f16x8 __attribute__((ext_vector_type(8)));
typedef float f32x4 __attribute__((ext_vector_type(4)));

// workspace layout (bytes)
#define OFF_LOGITS 0u                          // 65536 f32
#define OFF_TOPKI  (256u*1024u)                // 20480 int
#define OFF_TOPKW  (OFF_TOPKI + 128u*1024u)    // 20480 f32
#define OFF_COUNTS (OFF_TOPKW + 128u*1024u)    // 8192 f32
#define OFF_SCAL   (OFF_COUNTS + 64u*1024u)    // 16 f32
#define OFF_XH     (1u<<20)                    // 8192*1024 f16   (16.8 MB)
#define OFF_WT     (18u<<20)                   // 8*4096*1024 f16 (67.1 MB) — w1t then w2t (reused)
#define OFF_MID    (86u<<20)                   // 20480*4096 f16  (167.8 MB) → high-water ~254 MB

__device__ __forceinline__ void gl_lds16(const void* g, void* l) {
    __builtin_amdgcn_global_load_lds(
        (const __attribute__((address_space(1))) uint32_t*)g,
        (__attribute__((address_space(3))) uint32_t*)l, 16, 0, 0);
}

// ------------------------------------------------ router (+ x → f16 fused) --
// NOTE: summation order is frozen — top-k selection depends on exact fp32
// logit ordering near capacity boundaries. Do not restructure this reduce.
__global__ void k_router(const float* __restrict__ x, const float* __restrict__ rw,
                         float* __restrict__ logits, float* __restrict__ scal,
                         f16* __restrict__ xh) {
    __shared__ float rwt[E_ * H_];
    __shared__ float part[4][9];
    int tid = threadIdx.x;
    for (int i = tid; i < E_ * H_; i += 256) {
        int h = i >> 3, e = i & 7;
        rwt[e * H_ + h] = rw[i];
    }
    __syncthreads();
    int w = tid >> 6, lane = tid & 63;
    int t = blockIdx.x * 4 + w;
    const float* xr = x + (size_t)t * H_;
    f16* xhr = xh + ((size_t)t << 10);
    float acc[E_];
#pragma unroll
    for (int e = 0; e < E_; ++e) acc[e] = 0.f;
    for (int it = 0; it < H_ / 64; ++it) {
        int h = lane + it * 64;
        float xv = xr[h];
        xhr[h] = (f16)xv;
#pragma unroll
        for (int e = 0; e < E_; ++e) acc[e] += xv * rwt[e * H_ + h];
    }
#pragma unroll
    for (int off = 32; off > 0; off >>= 1)
#pragma unroll
        for (int e = 0; e < E_; ++e) acc[e] += __shfl_down(acc[e], off);
    if (lane == 0) {
        int b = t >> 11, s = t & 2047;
        float m = acc[0];
#pragma unroll
        for (int e = 1; e < E_; ++e) m = fmaxf(m, acc[e]);
        float z = 0.f, ps = 0.f;
        float p[E_];
#pragma unroll
        for (int e = 0; e < E_; ++e) {
            logits[(size_t)((b << 3) + e) * S_ + s] = acc[e];
            z += acc[e] * acc[e];
            p[e] = expf(acc[e] - m);
            ps += p[e];
        }
        part[w][0] = z;
#pragma unroll
        for (int e = 0; e < E_; ++e) part[w][1 + e] = p[e] / ps;
    }
    __syncthreads();
    if (tid < 9) {
        float v = part[0][tid] + part[1][tid] + part[2][tid] + part[3][tid];
        atomicAdd(&scal[tid], v);
    }
}

// ----------------------------------------------------------------- top-k ----
// Exact top-CAP via 8x8-bit radix select on distinct u64 keys (same set &
// tie-break as jax.lax.top_k; slot order irrelevant — atomic combine).
__global__ void __launch_bounds__(1024) k_topk(const float* __restrict__ logits,
                                               int* __restrict__ tki,
                                               float* __restrict__ tkw,
                                               float* __restrict__ counts) {
    int be = blockIdx.x;
    const float* row = logits + (size_t)be * S_;
    __shared__ unsigned hist[256];
    __shared__ unsigned long long wmax[16];
    __shared__ float wsum[16];
    __shared__ unsigned long long sh_prefix;
    __shared__ unsigned sh_rem;
    __shared__ unsigned long long sh_max;
    __shared__ float sh_stot;
    __shared__ unsigned sh_cnt;
    int tid = threadIdx.x;

    unsigned u0 = __float_as_uint(row[tid]);
    u0 = (u0 & 0x80000000u) ? ~u0 : (u0 | 0x80000000u);
    unsigned long long k0 = ((unsigned long long)u0 << 32) | (unsigned)(~tid);
    unsigned u1 = __float_as_uint(row[tid + 1024]);
    u1 = (u1 & 0x80000000u) ? ~u1 : (u1 | 0x80000000u);
    unsigned long long k1 = ((unsigned long long)u1 << 32) | (unsigned)(~(tid + 1024));

    if (tid == 0) { sh_cnt = 0; sh_rem = CAP; sh_prefix = 0; }
    unsigned long long m = k0 > k1 ? k0 : k1;
#pragma unroll
    for (int off = 32; off > 0; off >>= 1) {
        unsigned long long o = __shfl_down(m, off);
        if (o > m) m = o;
    }
    if ((tid & 63) == 0) wmax[tid >> 6] = m;
    __syncthreads();
    if (tid == 0) {
        unsigned long long mm = wmax[0];
#pragma unroll
        for (int i = 1; i < 16; ++i) if (wmax[i] > mm) mm = wmax[i];
        sh_max = mm;
    }

    unsigned long long prefix = 0;
    for (int L = 0; L < 8; ++L) {
        int shift = 56 - 8 * L;
        if (tid < 256) hist[tid] = 0;
        __syncthreads();
        bool m0 = (L == 0) || (((k0 ^ prefix) >> (shift + 8)) == 0);
        if (m0) atomicAdd(&hist[(unsigned)((k0 >> shift) & 255)], 1u);
        bool m1 = (L == 0) || (((k1 ^ prefix) >> (shift + 8)) == 0);
        if (m1) atomicAdd(&hist[(unsigned)((k1 >> shift) & 255)], 1u);
        __syncthreads();
        if (tid < 64) {
            unsigned g0 = hist[tid * 4], g1 = hist[tid * 4 + 1];
            unsigned g2 = hist[tid * 4 + 2], g3 = hist[tid * 4 + 3];
            unsigned gs = g0 + g1 + g2 + g3;
            unsigned suf = gs;
#pragma unroll
            for (int off = 1; off < 64; off <<= 1) {
                unsigned o = __shfl_down(suf, off);
                if (tid + off < 64) suf += o;
            }
            unsigned remaining = sh_rem;
            unsigned before = suf - gs;
            if (before < remaining && remaining <= suf) {
                unsigned cum = before;
                int bsel = tid * 4;
                unsigned rem2 = 0;
                for (int b = tid * 4 + 3; b >= tid * 4; --b) {
                    unsigned h = hist[b];
                    cum += h;
                    if (cum >= remaining) { bsel = b; rem2 = remaining - (cum - h); break; }
                }
                sh_prefix = prefix | ((unsigned long long)(unsigned)bsel << shift);
                sh_rem = rem2;
            }
        }
        __syncthreads();
        prefix = sh_prefix;
    }
    unsigned long long T = prefix;

    unsigned vu = (unsigned)(sh_max >> 32);
    float vmax = __uint_as_float((vu & 0x80000000u) ? (vu ^ 0x80000000u) : ~vu);

    float ex0 = 0.f, ex1 = 0.f;
    int idx0 = 0, idx1 = 0;
    if (k0 >= T) {
        idx0 = (int)(~(unsigned)k0) & 2047;
        unsigned vb = (unsigned)(k0 >> 32);
        float v = __uint_as_float((vb & 0x80000000u) ? (vb ^ 0x80000000u) : ~vb);
        ex0 = expf(v - vmax);
    }
    if (k1 >= T) {
        idx1 = (int)(~(unsigned)k1) & 2047;
        unsigned vb = (unsigned)(k1 >> 32);
        float v = __uint_as_float((vb & 0x80000000u) ? (vb ^ 0x80000000u) : ~vb);
        ex1 = expf(v - vmax);
    }
    float s = ex0 + ex1;
#pragma unroll
    for (int off = 32; off > 0; off >>= 1) s += __shfl_down(s, off);
    if ((tid & 63) == 0) wsum[tid >> 6] = s;
    __syncthreads();
    if (tid == 0) {
        float t2 = 0.f;
#pragma unroll
        for (int i = 0; i < 16; ++i) t2 += wsum[i];
        sh_stot = t2;
    }
    __syncthreads();
    float stot = sh_stot;
    if (k0 >= T) {
        unsigned slot = atomicAdd(&sh_cnt, 1u);
        tki[be * CAP + slot] = idx0;
        tkw[be * CAP + slot] = ex0 / stot;
        atomicAdd(&counts[(be >> 3) * S_ + idx0], 1.0f);
    }
    if (k1 >= T) {
        unsigned slot = atomicAdd(&sh_cnt, 1u);
        tki[be * CAP + slot] = idx1;
        tkw[be * CAP + slot] = ex1 / stot;
        atomicAdd(&counts[(be >> 3) * S_ + idx1], 1.0f);
    }
}

// in: [E][R][C] f32 → out: [E][C][R] f16
template<int R, int C>
__global__ void __launch_bounds__(256) k_transpose(const float* __restrict__ in,
                                                   f16* __restrict__ out) {
    __shared__ f16 t[64][68];
    int e = blockIdx.z;
    const float* ine = in + (size_t)e * R * C;
    f16* oute = out + (size_t)e * R * C;
    int c0 = blockIdx.x << 6, r0 = blockIdx.y << 6;
    int tx = threadIdx.x & 15, ty = threadIdx.x >> 4;
#pragma unroll
    for (int p = 0; p < 4; ++p) {
        int r = ty + p * 16;
        float4 v = *(const float4*)(ine + (size_t)(r0 + r) * C + c0 + tx * 4);
        t[tx * 4 + 0][r] = (f16)v.x;
        t[tx * 4 + 1][r] = (f16)v.y;
        t[tx * 4 + 2][r] = (f16)v.z;
        t[tx * 4 + 3][r] = (f16)v.w;
    }
    __syncthreads();
#pragma unroll
    for (int p = 0; p < 4; ++p) {
        int c = ty + p * 16;
        *(ushort4*)(oute + (size_t)(c0 + c) * R + r0 + tx * 4) =
            *(const ushort4*)&t[c][tx * 4];
    }
}

// ============================ GEMM core geometry =============================
// EVIDENCE (R2-R14): perf tracks blocks/CU; every schedule/pipeline variant
// regressed or neutral; gemm2 tail fixes failed (R13 atomics ×4; R14 B-reuse
// halved → FETCH ×2; M=160 unschedulable: 140 regs × 16 waves > 2048).
// R12 = empirical optimum: 128x128 tile, BK=64, single 32KB LDS buffer
// (8-slot XOR swizzle → 0 conflicts), (256,4), 124 unified regs → 4 blk/CU,
// stage → sync → 32 MFMA → sync. Rows expert-major; expert == XCD chunk
// (ideal FETCH). Fast-SiLU epilogue (v_exp+v_rcp).

#define MFMA4(MI, A) \
    acc[MI][0] = __builtin_amdgcn_mfma_f32_16x16x32_f16(A, bf0, acc[MI][0], 0, 0, 0); \
    acc[MI][1] = __builtin_amdgcn_mfma_f32_16x16x32_f16(A, bf1, acc[MI][1], 0, 0, 0); \
    acc[MI][2] = __builtin_amdgcn_mfma_f32_16x16x32_f16(A, bf2, acc[MI][2], 0, 0, 0); \
    acc[MI][3] = __builtin_amdgcn_mfma_f32_16x16x32_f16(A, bf3, acc[MI][3], 0, 0, 0);

// ---------------------------------------------------------- GEMM1 (+SiLU) ---
// grid 5120 = 8 e × 20 rt × 32 ct; XCD chunk = one expert (640 blocks).
__global__ void __launch_bounds__(256, 4) k_gemm1(const f16* __restrict__ xh,
                                                  const f16* __restrict__ w1t,
                                                  const int* __restrict__ tki,
                                                  f16* __restrict__ mid) {
    __shared__ f16 As[128 * 64];   // 16 KB
    __shared__ f16 Bs[128 * 64];   // 16 KB
    int bid = blockIdx.x;
    int e = bid & 7;
    int r = bid >> 3;              // 0..639 within expert chunk
    int rt = r % 20;
    int ct = r / 20;               // 0..31
    int n0 = ct << 7;
    const f16* w1e = w1t + ((size_t)e << 22);
    int tid = threadIdx.x;
    int w = tid >> 6, l = tid & 63;
    int wm = w >> 1, wn = w & 1;

    int gch = (tid & 7) ^ ((tid >> 3) & 7);
    int dstb = (tid >> 6) << 9;    // wave-uniform f16 base; HW adds lane*16B
    const f16* aS[4];
    const f16* bS[4];
#pragma unroll
    for (int i = 0; i < 4; ++i) {
        int ri = i * 32 + (tid >> 3);
        int ge = rt * 128 + ri;
        int bb = ge / 640;
        int cc = ge - bb * 640;
        int tok = tki[((bb << 3) + e) * 640 + cc];
        aS[i] = xh + ((size_t)((bb << 11) + tok) << 10) + (gch << 3);
        bS[i] = w1e + ((size_t)(n0 + ri) << 10) + (gch << 3);
    }

    int fr = l & 15, c4 = l >> 4;
    int f7 = fr & 7;
    int arow = (wm << 6) + fr;
    int brow = (wn << 6) + fr;
    f32x4 acc[4][4];
#pragma unroll
    for (int mi = 0; mi < 4; ++mi)
#pragma unroll
        for (int ni = 0; ni < 4; ++ni) acc[mi][ni] = (f32x4){0.f, 0.f, 0.f, 0.f};

    const int NT = H_ / 64;   // 16
    for (int t = 0; t < NT; ++t) {
        int ko = t << 6;
#pragma unroll
        for (int i = 0; i < 4; ++i) {
            gl_lds16(aS[i] + ko, As + i * 2048 + dstb);
            gl_lds16(bS[i] + ko, Bs + i * 2048 + dstb);
        }
        __syncthreads();
#pragma unroll
        for (int kf = 0; kf < 2; ++kf) {
            int sl = (((kf << 2) | c4) ^ f7) << 3;
            f16x8 bf0 = *(const f16x8*)(Bs + brow * 64 + sl);
            f16x8 bf1 = *(const f16x8*)(Bs + (brow + 16) * 64 + sl);
            f16x8 bf2 = *(const f16x8*)(Bs + (brow + 32) * 64 + sl);
            f16x8 bf3 = *(const f16x8*)(Bs + (brow + 48) * 64 + sl);
            f16x8 a0 = *(const f16x8*)(As + arow * 64 + sl);
            f16x8 a1 = *(const f16x8*)(As + (arow + 16) * 64 + sl);
            f16x8 a2 = *(const f16x8*)(As + (arow + 32) * 64 + sl);
            f16x8 a3 = *(const f16x8*)(As + (arow + 48) * 64 + sl);
            MFMA4(0, a0) MFMA4(1, a1) MFMA4(2, a2) MFMA4(3, a3)
        }
        __syncthreads();
    }

    // epilogue: FAST SiLU (v_exp + v_rcp; rel err ~1e-6 << f16 quantization)
    int rq4 = c4 << 2;
#pragma unroll
    for (int mi = 0; mi < 4; ++mi) {
#pragma unroll
        for (int q = 0; q < 4; ++q) {
            int row = (wm << 6) + mi * 16 + rq4 + q;
            int ge = rt * 128 + row;
            int bb = ge / 640;
            int cc = ge - bb * 640;
            size_t flat = (size_t)(((bb << 3) + e) * 640 + cc);
            f16* mrow = mid + (flat << 12) + n0 + (wn << 6) + fr;
#pragma unroll
            for (int ni = 0; ni < 4; ++ni) {
                float v = acc[mi][ni][q];
                v = v * __builtin_amdgcn_rcpf(1.f + __expf(-v));
                mrow[ni * 16] = (f16)v;
            }
        }
    }
}

// ------------------------------------------- GEMM2 + weighted atomic scatter
// grid 1280 = 8 e × 20 rt × 8 ct; XCD chunk = one expert (160 blocks).
// LDS exactly 32768 B: toks/wts staged into dead As space AFTER the K-loop.
__global__ void __launch_bounds__(256, 4) k_gemm2(const f16* __restrict__ mid,
                                                  const f16* __restrict__ w2t,
                                                  const int* __restrict__ tki,
                                                  const float* __restrict__ tkw,
                                                  float* __restrict__ out) {
    __shared__ f16 As[128 * 64];
    __shared__ f16 Bs[128 * 64];
    int bid = blockIdx.x;
    int e = bid & 7;
    int r = bid >> 3;              // 0..159
    int rt = r % 20;
    int ct = r / 20;               // 0..7
    int n0 = ct << 7;
    const f16* w2e = w2t + ((size_t)e << 22);
    int tid = threadIdx.x;
    int w = tid >> 6, l = tid & 63;
    int wm = w >> 1, wn = w & 1;

    int gch = (tid & 7) ^ ((tid >> 3) & 7);
    int dstb = (tid >> 6) << 9;
    const f16* aS[4];
    const f16* bS[4];
#pragma unroll
    for (int i = 0; i < 4; ++i) {
        int ri = i * 32 + (tid >> 3);
        int ge = rt * 128 + ri;
        int bb = ge / 640;
        int cc = ge - bb * 640;
        size_t flat = (size_t)(((bb << 3) + e) * 640 + cc);
        aS[i] = mid + (flat << 12) + (gch << 3);
        bS[i] = w2e + ((size_t)(n0 + ri) << 12) + (gch << 3);
    }

    int fr = l & 15, c4 = l >> 4;
    int f7 = fr & 7;
    int arow = (wm << 6) + fr;
    int brow = (wn << 6) + fr;
    f32x4 acc[4][4];
#pragma unroll
    for (int mi = 0; mi < 4; ++mi)
#pragma unroll
        for (int ni = 0; ni < 4; ++ni) acc[mi][ni] = (f32x4){0.f, 0.f, 0.f, 0.f};

    const int NT = I_ / 64;   // 64
    for (int t = 0; t < NT; ++t) {
        int ko = t << 6;
#pragma unroll
        for (int i = 0; i < 4; ++i) {
            gl_lds16(aS[i] + ko, As + i * 2048 + dstb);
            gl_lds16(bS[i] + ko, Bs + i * 2048 + dstb);
        }
        __syncthreads();
#pragma unroll
        for (int kf = 0; kf < 2; ++kf) {
            int sl = (((kf << 2) | c4) ^ f7) << 3;
            f16x8 bf0 = *(const f16x8*)(Bs + brow * 64 + sl);
            f16x8 bf1 = *(const f16x8*)(Bs + (brow + 16) * 64 + sl);
            f16x8 bf2 = *(const f16x8*)(Bs + (brow + 32) * 64 + sl);
            f16x8 bf3 = *(const f16x8*)(Bs + (brow + 48) * 64 + sl);
            f16x8 a0 = *(const f16x8*)(As + arow * 64 + sl);
            f16x8 a1 = *(const f16x8*)(As + (arow + 16) * 64 + sl);
            f16x8 a2 = *(const f16x8*)(As + (arow + 32) * 64 + sl);
            f16x8 a3 = *(const f16x8*)(As + (arow + 48) * 64 + sl);
            MFMA4(0, a0) MFMA4(1, a1) MFMA4(2, a2) MFMA4(3, a3)
        }
        __syncthreads();
    }

    // stage row offsets/weights into dead LDS (As is free after final barrier)
    int* rowOffS = (int*)As;              // 512 B
    float* wtsS = (float*)(As + 256);     // 512 B
    if (tid < 128) {
        int ge = rt * 128 + tid;
        int bb = ge / 640;
        int cc = ge - bb * 640;
        int flat = ((bb << 3) + e) * 640 + cc;
        rowOffS[tid] = ((bb << 11) + tki[flat]) << 10;
        wtsS[tid] = tkw[flat];
    }
    __syncthreads();

    int rq4 = c4 << 2;
#pragma unroll
    for (int mi = 0; mi < 4; ++mi) {
#pragma unroll
        for (int q = 0; q < 4; ++q) {
            int row = (wm << 6) + mi * 16 + rq4 + q;
            int ro = rowOffS[row] + n0 + (wn << 6) + fr;
            float wg = wtsS[row];
#pragma unroll
            for (int ni = 0; ni < 4; ++ni) {
                atomicAdd(&out[ro + ni * 16], acc[mi][ni][q] * wg);
            }
        }
    }
}

// ------------------------------------------------- normalize + loss ---------
__global__ void k_final(float* __restrict__ out, const float* __restrict__ counts,
                        const float* __restrict__ scal, float* __restrict__ loss_out) {
    size_t gid = (size_t)blockIdx.x * 256 + threadIdx.x;
    int tok = (int)(gid >> 8);
    float c = fmaxf(counts[tok], 1.0f);
    float4* o4 = (float4*)out;
    float4 v = o4[gid];
    v.x /= c; v.y /= c; v.z /= c; v.w /= c;
    o4[gid] = v;
    if (gid == 0) {
        float z = scal[0] / (float)(NTOK * E_);
        float aux = 0.f;
#pragma unroll
        for (int e = 0; e < E_; ++e) {
            float u = scal[1 + e] / (float)NTOK - 0.125f;
            aux += u * u;
        }
        loss_out[0] = 0.01f * aux + 0.001f * z;
    }
}

// ----------------------------------------------------------------------------
extern "C" void kernel_launch(void* const* d_in, const int* in_sizes, int n_in,
                              void* d_out, int out_size, void* d_ws, size_t ws_size,
                              hipStream_t stream) {
    const float* x  = (const float*)d_in[0];
    const float* rw = (const float*)d_in[1];
    const float* w1 = (const float*)d_in[2];
    const float* w2 = (const float*)d_in[3];
    float* out = (float*)d_out;
    char* ws = (char*)d_ws;

    float* logits = (float*)(ws + OFF_LOGITS);
    int*   tki    = (int*)(ws + OFF_TOPKI);
    float* tkw    = (float*)(ws + OFF_TOPKW);
    float* counts = (float*)(ws + OFF_COUNTS);
    float* scal   = (float*)(ws + OFF_SCAL);
    f16*   xh     = (f16*)(ws + OFF_XH);
    f16*   wt     = (f16*)(ws + OFF_WT);     // w1t, then reused as w2t
    f16*   mid    = (f16*)(ws + OFF_MID);

    hipMemsetAsync(ws + OFF_COUNTS, 0, 64u * 1024u + 64u, stream);
    hipMemsetAsync(d_out, 0, (size_t)out_size * sizeof(float), stream);

    k_transpose<H_, I_><<<dim3(I_ / 64, H_ / 64, E_), 256, 0, stream>>>(w1, wt);
    k_router<<<NTOK / 4, 256, 0, stream>>>(x, rw, logits, scal, xh);
    k_topk<<<NBE, 1024, 0, stream>>>(logits, tki, tkw, counts);
    k_gemm1<<<5120, 256, 0, stream>>>(xh, wt, tki, mid);
    // reuse WT region for w2t (stream-ordered after gemm1 finished reading w1t)
    k_transpose<I_, H_><<<dim3(H_ / 64, I_ / 64, E_), 256, 0, stream>>>(w2, wt);
    k_gemm2<<<1280, 256, 0, stream>>>(mid, wt, tki, tkw, out);
    k_final<<<(NTOK * H_ / 4) / 256, 256, 0, stream>>>(out, counts, scal,
                                                       out + (size_t)NTOK * H_);
}